// Round 4
// baseline (2674.818 us; speedup 1.0000x reference)
//
#include <hip/hip_runtime.h>

namespace {

constexpr int NNODES = 50000;
constexpr int NEDGES = 800000;
constexpr int DIN  = 64;
constexpr int DOUT = 64;
constexpr int NBLK = (NNODES + 255) / 256;  // 196 scan blocks

// ---------------------------------------------------------------------------
// Detect whether edge_index arrived as int64 (odd 32-bit words all zero,
// since values < 50000) or int32 (odd words are values, ~never zero).
__global__ __launch_bounds__(256) void detect_idx64(const unsigned int* __restrict__ raw,
                                                    int* __restrict__ flag) {
  __shared__ int s_any;
  if (threadIdx.x == 0) s_any = 0;
  __syncthreads();
  int any = 0;
  for (int i = 1 + 2 * (int)threadIdx.x; i < 8192; i += 512) {
    any |= (raw[i] != 0u) ? 1 : 0;
  }
  if (any) atomicOr(&s_any, 1);
  __syncthreads();
  if (threadIdx.x == 0) *flag = (s_any == 0) ? 1 : 0;
}

// Degree histogram straight from raw edge_index (either width).
__global__ __launch_bounds__(256) void deg_hist(const void* __restrict__ raw,
                                                const int* __restrict__ flag,
                                                int* __restrict__ deg) {
  const int is64 = *flag;  // uniform branch
  const int stride = gridDim.x * blockDim.x;
  for (int e = blockIdx.x * blockDim.x + threadIdx.x; e < NEDGES; e += stride) {
    int d;
    if (is64) {
      d = (int)((const long long*)raw)[NEDGES + e];
    } else {
      d = ((const int*)raw)[NEDGES + e];
    }
    atomicAdd(&deg[d], 1);
  }
}

// --- Hierarchical exclusive scan of deg[NNODES] ----------------------------
__global__ __launch_bounds__(256) void scan_phase1(const int* __restrict__ deg,
                                                   int* __restrict__ bsum) {
  const int idx = blockIdx.x * 256 + threadIdx.x;
  int v = (idx < NNODES) ? deg[idx] : 0;
  const int lane = threadIdx.x & 63;
  const int w = threadIdx.x >> 6;
#pragma unroll
  for (int off = 32; off; off >>= 1) v += __shfl_down(v, off, 64);
  __shared__ int wsum[4];
  if (lane == 0) wsum[w] = v;
  __syncthreads();
  if (threadIdx.x == 0) bsum[blockIdx.x] = wsum[0] + wsum[1] + wsum[2] + wsum[3];
}

__global__ __launch_bounds__(256) void scan_phase2(int* __restrict__ bsum,
                                                   int* __restrict__ row_ptr) {
  __shared__ int sh[256];
  const int t = threadIdx.x;
  const int v = (t < NBLK) ? bsum[t] : 0;
  sh[t] = v;
  __syncthreads();
#pragma unroll
  for (int off = 1; off < 256; off <<= 1) {
    const int val = sh[t];
    const int add = (t >= off) ? sh[t - off] : 0;
    __syncthreads();
    sh[t] = val + add;
    __syncthreads();
  }
  if (t < NBLK) bsum[t] = sh[t] - v;  // exclusive
  if (t == 255) row_ptr[NNODES] = sh[255];
}

__global__ __launch_bounds__(256) void scan_phase3(const int* __restrict__ deg,
                                                   const int* __restrict__ bsum,
                                                   int* __restrict__ row_ptr,
                                                   int* __restrict__ cursor) {
  const int idx = blockIdx.x * 256 + threadIdx.x;
  const int v = (idx < NNODES) ? deg[idx] : 0;
  const int lane = threadIdx.x & 63;
  const int w = threadIdx.x >> 6;
  int s = v;  // inclusive scan within wave
#pragma unroll
  for (int off = 1; off < 64; off <<= 1) {
    const int t = __shfl_up(s, off, 64);
    if (lane >= off) s += t;
  }
  __shared__ int wsum[4];
  if (lane == 63) wsum[w] = s;
  __syncthreads();
  int wo = 0;
  for (int i = 0; i < 4; ++i) wo += (i < w) ? wsum[i] : 0;
  const int excl = bsum[blockIdx.x] + wo + (s - v);
  if (idx < NNODES) {
    row_ptr[idx] = excl;
    cursor[idx] = excl;
  }
}

// Fill CSR column list straight from raw edge_index via atomic cursors.
__global__ __launch_bounds__(256) void fill_csr(const void* __restrict__ raw,
                                                const int* __restrict__ flag,
                                                int* __restrict__ cursor,
                                                int* __restrict__ col) {
  const int is64 = *flag;
  const int stride = gridDim.x * blockDim.x;
  for (int e = blockIdx.x * blockDim.x + threadIdx.x; e < NEDGES; e += stride) {
    int s, d;
    if (is64) {
      const long long* p = (const long long*)raw;
      s = (int)p[e];
      d = (int)p[NEDGES + e];
    } else {
      const int* p = (const int*)raw;
      s = p[e];
      d = p[NEDGES + e];
    }
    const int slot = atomicAdd(&cursor[d], 1);
    col[slot] = s;
  }
}

// Segment mean via gather: one wave (64 lanes == D channels) per node.
template <int D, bool FINAL>
__global__ __launch_bounds__(256) void seg_mean(const float* __restrict__ xin,
                                                const int* __restrict__ row_ptr,
                                                const int* __restrict__ col,
                                                const float* __restrict__ radd,
                                                float* __restrict__ outbuf) {
  static_assert(D == 64, "one wave == one node's 64 channels");
  const int lane = threadIdx.x & 63;
  const int wid = (blockIdx.x * blockDim.x + threadIdx.x) >> 6;
  const int nw = (gridDim.x * blockDim.x) >> 6;
  for (int v = wid; v < NNODES; v += nw) {
    const int b = row_ptr[v];
    const int e = row_ptr[v + 1];
    float acc = 0.0f;
    int i = b;
    for (; i + 4 <= e; i += 4) {  // unroll x4: 4 independent gathers in flight
      const int s0 = col[i], s1 = col[i + 1], s2 = col[i + 2], s3 = col[i + 3];
      const float v0 = xin[(size_t)s0 * D + lane];
      const float v1 = xin[(size_t)s1 * D + lane];
      const float v2 = xin[(size_t)s2 * D + lane];
      const float v3 = xin[(size_t)s3 * D + lane];
      acc += (v0 + v1) + (v2 + v3);
    }
    for (; i < e; ++i) acc += xin[(size_t)col[i] * D + lane];
    const float inv = 1.0f / fmaxf((float)(e - b), 1.0f);
    float val = acc * inv;
    if (FINAL) val += radd[(size_t)v * D + lane];
    outbuf[(size_t)v * D + lane] = val;
  }
}

// ---------------------------------------------------------------------------
// Register-tiled fp32 GEMM: C[50000 x 128] = A[50000 x 128] @ W[128 x 128].
// MODE 0 (layer 1): A = [mean1 | x] (two 64-wide buffers),
//                   W = [Wl1 ; Wr1] (two 64x128), out = relu(C + bias) -> O0[N,128]
// MODE 1 (layer 2): A = h [N,128],
//                   W = [Wl2 | Wr2] (two 128x64),
//                   O0[N,64] = C[:,0:64] (p, no bias); O1[N,64] = C[:,64:128] + bias (r)
// Block: 256 threads, BM=64 rows, BN=128 (all), BK=32 (4 chunks).
// Thread tile: 4 rows x 8 cols (cols j0..j0+3 and 64+j0..64+j0+3).
template <int MODE>
__global__ __launch_bounds__(256) void gemm128(const float* __restrict__ A0,
                                               const float* __restrict__ A1,
                                               const float* __restrict__ W0,
                                               const float* __restrict__ W1,
                                               const float* __restrict__ bias,
                                               float* __restrict__ O0,
                                               float* __restrict__ O1) {
  constexpr int SAS = 36;  // sA row stride (pad 32->36: rows land on distinct banks)
  __shared__ float sA[64][SAS];
  __shared__ float sW[32][128];
  const int row0 = blockIdx.x * 64;
  const int tid = threadIdx.x;
  const int rowgrp = tid >> 4;   // 0..15
  const int colgrp = tid & 15;   // 0..15
  const int r0 = rowgrp * 4;
  const int j0 = colgrp * 4;

  float accA[4][4];  // cols j0..j0+3
  float accB[4][4];  // cols 64+j0..64+j0+3
#pragma unroll
  for (int r = 0; r < 4; ++r)
#pragma unroll
    for (int c = 0; c < 4; ++c) { accA[r][c] = 0.0f; accB[r][c] = 0.0f; }

#pragma unroll
  for (int ck = 0; ck < 4; ++ck) {
    // --- stage sA: 64 rows x 32 k ---
#pragma unroll
    for (int v = 0; v < 2; ++v) {
      const int vid = v * 256 + tid;       // 0..511
      const int rr = vid >> 3;             // 0..63
      const int kq = (vid & 7) * 4;        // 0,4,...,28
      const int grow = row0 + rr;
      float4 val = make_float4(0.f, 0.f, 0.f, 0.f);
      if (grow < NNODES) {
        if (MODE == 0) {
          const float* src = (ck < 2) ? A0 : A1;
          const int kk = (ck & 1) * 32 + kq;
          val = *(const float4*)&src[(size_t)grow * 64 + kk];
        } else {
          val = *(const float4*)&A0[(size_t)grow * 128 + ck * 32 + kq];
        }
      }
      *(float4*)&sA[rr][kq] = val;
    }
    // --- stage sW: 32 k x 128 j ---
#pragma unroll
    for (int v = 0; v < 4; ++v) {
      const int vid = v * 256 + tid;       // 0..1023
      const int kk = vid >> 5;             // 0..31
      const int jq = (vid & 31) * 4;       // 0,4,...,124
      float4 w;
      if (MODE == 0) {
        const float* src = (ck < 2) ? W0 : W1;
        const int krel = (ck & 1) * 32 + kk;
        w = *(const float4*)&src[(size_t)krel * 128 + jq];
      } else {
        const int kg = ck * 32 + kk;
        const float* src = (jq < 64) ? W0 : W1;
        const int jrel = (jq < 64) ? jq : jq - 64;
        w = *(const float4*)&src[(size_t)kg * 64 + jrel];
      }
      *(float4*)&sW[kk][jq] = w;
    }
    __syncthreads();
    // --- compute: 32 k's, 128 FMA per 4-k group per thread ---
#pragma unroll
    for (int k4 = 0; k4 < 8; ++k4) {
      float4 a[4];
#pragma unroll
      for (int r = 0; r < 4; ++r) a[r] = *(const float4*)&sA[r0 + r][k4 * 4];
#pragma unroll
      for (int ki = 0; ki < 4; ++ki) {
        const float4 wlo = *(const float4*)&sW[k4 * 4 + ki][j0];
        const float4 whi = *(const float4*)&sW[k4 * 4 + ki][64 + j0];
#pragma unroll
        for (int r = 0; r < 4; ++r) {
          const float av = (ki == 0) ? a[r].x : (ki == 1) ? a[r].y
                         : (ki == 2) ? a[r].z : a[r].w;
          accA[r][0] = fmaf(av, wlo.x, accA[r][0]);
          accA[r][1] = fmaf(av, wlo.y, accA[r][1]);
          accA[r][2] = fmaf(av, wlo.z, accA[r][2]);
          accA[r][3] = fmaf(av, wlo.w, accA[r][3]);
          accB[r][0] = fmaf(av, whi.x, accB[r][0]);
          accB[r][1] = fmaf(av, whi.y, accB[r][1]);
          accB[r][2] = fmaf(av, whi.z, accB[r][2]);
          accB[r][3] = fmaf(av, whi.w, accB[r][3]);
        }
      }
    }
    __syncthreads();
  }

  // --- epilogue ---
  float4 blo = make_float4(0.f, 0.f, 0.f, 0.f);
  float4 bhi;
  if (MODE == 0) {
    blo = *(const float4*)&bias[j0];
    bhi = *(const float4*)&bias[64 + j0];
  } else {
    bhi = *(const float4*)&bias[j0];  // bias applies to r (upper half)
  }
#pragma unroll
  for (int r = 0; r < 4; ++r) {
    const int grow = row0 + r0 + r;
    if (grow >= NNODES) continue;
    float4 lo = make_float4(accA[r][0] + blo.x, accA[r][1] + blo.y,
                            accA[r][2] + blo.z, accA[r][3] + blo.w);
    float4 hi = make_float4(accB[r][0] + bhi.x, accB[r][1] + bhi.y,
                            accB[r][2] + bhi.z, accB[r][3] + bhi.w);
    if (MODE == 0) {
      lo.x = fmaxf(lo.x, 0.f); lo.y = fmaxf(lo.y, 0.f);
      lo.z = fmaxf(lo.z, 0.f); lo.w = fmaxf(lo.w, 0.f);
      hi.x = fmaxf(hi.x, 0.f); hi.y = fmaxf(hi.y, 0.f);
      hi.z = fmaxf(hi.z, 0.f); hi.w = fmaxf(hi.w, 0.f);
      *(float4*)&O0[(size_t)grow * 128 + j0] = lo;
      *(float4*)&O0[(size_t)grow * 128 + 64 + j0] = hi;
    } else {
      *(float4*)&O0[(size_t)grow * 64 + j0] = lo;   // p (no bias; blo==0)
      *(float4*)&O1[(size_t)grow * 64 + j0] = hi;   // r (+bl2)
    }
  }
}

}  // namespace

extern "C" void kernel_launch(void* const* d_in, const int* in_sizes, int n_in,
                              void* d_out, int out_size, void* d_ws, size_t ws_size,
                              hipStream_t stream) {
  const float* x   = (const float*)d_in[0];
  const void*  ei  = d_in[1];  // edge_index, int32 or int64 (detected at runtime)
  const float* Wl1 = (const float*)d_in[2];
  const float* bl1 = (const float*)d_in[3];
  const float* Wr1 = (const float*)d_in[4];
  const float* Wl2 = (const float*)d_in[5];
  const float* bl2 = (const float*)d_in[6];
  const float* Wr2 = (const float*)d_in[7];
  float* out = (float*)d_out;

  // Workspace layout (bytes):
  //   col     [E]    int32 @ 0          (3,200,000)
  //   flag    [1]    int32 @ 3,200,000  (256)
  //   deg     [N]    int32 @ 3,200,256  (200,000)   <- only memset target
  //   row_ptr [N+1]  int32 @ 3,400,256  (200,064)
  //   cursor  [N]    int32 @ 3,600,320  (200,000)
  //   bsum    [NBLK] int32 @ 3,800,320  (1,024 padded)
  //   mean1   [N,64] f32   @ 3,801,344  (12,800,000)  -- reused as r
  //   h       [N,128]f32   @ 16,601,344 (25,600,000)
  //   p       [N,64] f32   @ 42,201,344 (12,800,000)
  // total: 55,001,344 bytes
  char* ws = (char*)d_ws;
  int*   col     = (int*)(ws + 0);
  int*   flag    = (int*)(ws + 3200000);
  int*   deg     = (int*)(ws + 3200256);
  int*   row_ptr = (int*)(ws + 3400256);
  int*   cursor  = (int*)(ws + 3600320);
  int*   bsum    = (int*)(ws + 3800320);
  float* mean1   = (float*)(ws + 3801344);
  float* h       = (float*)(ws + 16601344);
  float* p       = (float*)(ws + 42201344);
  float* r       = mean1;  // safe: mean1's last read (gemm128<0>) precedes gemm128<1>'s write

  hipMemsetAsync(deg, 0, 200000, stream);

  // CSR build
  detect_idx64<<<1, 256, 0, stream>>>((const unsigned int*)ei, flag);
  deg_hist<<<1024, 256, 0, stream>>>(ei, flag, deg);
  scan_phase1<<<NBLK, 256, 0, stream>>>(deg, bsum);
  scan_phase2<<<1, 256, 0, stream>>>(bsum, row_ptr);
  scan_phase3<<<NBLK, 256, 0, stream>>>(deg, bsum, row_ptr, cursor);
  fill_csr<<<1024, 256, 0, stream>>>(ei, flag, cursor, col);

  constexpr int GEMM_BLOCKS = (NNODES + 63) / 64;  // 782

  // Layer 1: mean-aggregate x (gather, no atomics), then fused linear+relu
  seg_mean<DIN, false><<<12500, 256, 0, stream>>>(x, row_ptr, col, nullptr, mean1);
  gemm128<0><<<GEMM_BLOCKS, 256, 0, stream>>>(mean1, x, Wl1, Wr1, bl1, h, nullptr);

  // Layer 2: project first (mean commutes with linear), then gather + fused add
  gemm128<1><<<GEMM_BLOCKS, 256, 0, stream>>>(h, nullptr, Wl2, Wr2, bl2, p, r);
  seg_mean<DOUT, true><<<12500, 256, 0, stream>>>(p, row_ptr, col, r, out);
}

// Round 5
// 230.043 us; speedup vs baseline: 11.6275x; 11.6275x over previous
//
#include <hip/hip_runtime.h>

namespace {

constexpr int NNODES = 50000;
constexpr int NEDGES = 800000;
constexpr int DIN  = 64;
constexpr int DOUT = 64;
constexpr int NBLK = (NNODES + 255) / 256;  // 196 scan blocks

// ---------------------------------------------------------------------------
// Detect whether edge_index arrived as int64 (odd 32-bit words all zero,
// since values < 50000) or int32 (odd words are values, ~never zero).
__global__ __launch_bounds__(256) void detect_idx64(const unsigned int* __restrict__ raw,
                                                    int* __restrict__ flag) {
  __shared__ int s_any;
  if (threadIdx.x == 0) s_any = 0;
  __syncthreads();
  int any = 0;
  for (int i = 1 + 2 * (int)threadIdx.x; i < 8192; i += 512) {
    any |= (raw[i] != 0u) ? 1 : 0;
  }
  if (any) atomicOr(&s_any, 1);
  __syncthreads();
  if (threadIdx.x == 0) *flag = (s_any == 0) ? 1 : 0;
}

// Degree histogram straight from raw edge_index (either width).
__global__ __launch_bounds__(256) void deg_hist(const void* __restrict__ raw,
                                                const int* __restrict__ flag,
                                                int* __restrict__ deg) {
  const int is64 = *flag;  // uniform branch
  const int stride = gridDim.x * blockDim.x;
  for (int e = blockIdx.x * blockDim.x + threadIdx.x; e < NEDGES; e += stride) {
    int d;
    if (is64) {
      d = (int)((const long long*)raw)[NEDGES + e];
    } else {
      d = ((const int*)raw)[NEDGES + e];
    }
    atomicAdd(&deg[d], 1);
  }
}

// --- Hierarchical exclusive scan of deg[NNODES] ----------------------------
__global__ __launch_bounds__(256) void scan_phase1(const int* __restrict__ deg,
                                                   int* __restrict__ bsum) {
  const int idx = blockIdx.x * 256 + threadIdx.x;
  int v = (idx < NNODES) ? deg[idx] : 0;
  const int lane = threadIdx.x & 63;
  const int w = threadIdx.x >> 6;
#pragma unroll
  for (int off = 32; off; off >>= 1) v += __shfl_down(v, off, 64);
  __shared__ int wsum[4];
  if (lane == 0) wsum[w] = v;
  __syncthreads();
  if (threadIdx.x == 0) bsum[blockIdx.x] = wsum[0] + wsum[1] + wsum[2] + wsum[3];
}

__global__ __launch_bounds__(256) void scan_phase2(int* __restrict__ bsum,
                                                   int* __restrict__ row_ptr) {
  __shared__ int sh[256];
  const int t = threadIdx.x;
  const int v = (t < NBLK) ? bsum[t] : 0;
  sh[t] = v;
  __syncthreads();
#pragma unroll
  for (int off = 1; off < 256; off <<= 1) {
    const int val = sh[t];
    const int add = (t >= off) ? sh[t - off] : 0;
    __syncthreads();
    sh[t] = val + add;
    __syncthreads();
  }
  if (t < NBLK) bsum[t] = sh[t] - v;  // exclusive
  if (t == 255) row_ptr[NNODES] = sh[255];
}

__global__ __launch_bounds__(256) void scan_phase3(const int* __restrict__ deg,
                                                   const int* __restrict__ bsum,
                                                   int* __restrict__ row_ptr,
                                                   int* __restrict__ cursor) {
  const int idx = blockIdx.x * 256 + threadIdx.x;
  const int v = (idx < NNODES) ? deg[idx] : 0;
  const int lane = threadIdx.x & 63;
  const int w = threadIdx.x >> 6;
  int s = v;  // inclusive scan within wave
#pragma unroll
  for (int off = 1; off < 64; off <<= 1) {
    const int t = __shfl_up(s, off, 64);
    if (lane >= off) s += t;
  }
  __shared__ int wsum[4];
  if (lane == 63) wsum[w] = s;
  __syncthreads();
  int wo = 0;
  for (int i = 0; i < 4; ++i) wo += (i < w) ? wsum[i] : 0;
  const int excl = bsum[blockIdx.x] + wo + (s - v);
  if (idx < NNODES) {
    row_ptr[idx] = excl;
    cursor[idx] = excl;
  }
}

// Fill CSR column list straight from raw edge_index via atomic cursors.
__global__ __launch_bounds__(256) void fill_csr(const void* __restrict__ raw,
                                                const int* __restrict__ flag,
                                                int* __restrict__ cursor,
                                                int* __restrict__ col) {
  const int is64 = *flag;
  const int stride = gridDim.x * blockDim.x;
  for (int e = blockIdx.x * blockDim.x + threadIdx.x; e < NEDGES; e += stride) {
    int s, d;
    if (is64) {
      const long long* p = (const long long*)raw;
      s = (int)p[e];
      d = (int)p[NEDGES + e];
    } else {
      const int* p = (const int*)raw;
      s = p[e];
      d = p[NEDGES + e];
    }
    const int slot = atomicAdd(&cursor[d], 1);
    col[slot] = s;
  }
}

// Segment mean via gather: one wave (64 lanes == D channels) per node.
template <int D, bool FINAL>
__global__ __launch_bounds__(256) void seg_mean(const float* __restrict__ xin,
                                                const int* __restrict__ row_ptr,
                                                const int* __restrict__ col,
                                                const float* __restrict__ radd,
                                                float* __restrict__ outbuf) {
  static_assert(D == 64, "one wave == one node's 64 channels");
  const int lane = threadIdx.x & 63;
  const int wid = (blockIdx.x * blockDim.x + threadIdx.x) >> 6;
  const int nw = (gridDim.x * blockDim.x) >> 6;
  for (int v = wid; v < NNODES; v += nw) {
    const int b = row_ptr[v];
    const int e = row_ptr[v + 1];
    float acc = 0.0f;
    int i = b;
    for (; i + 4 <= e; i += 4) {  // unroll x4: 4 independent gathers in flight
      const int s0 = col[i], s1 = col[i + 1], s2 = col[i + 2], s3 = col[i + 3];
      const float v0 = xin[(size_t)s0 * D + lane];
      const float v1 = xin[(size_t)s1 * D + lane];
      const float v2 = xin[(size_t)s2 * D + lane];
      const float v3 = xin[(size_t)s3 * D + lane];
      acc += (v0 + v1) + (v2 + v3);
    }
    for (; i < e; ++i) acc += xin[(size_t)col[i] * D + lane];
    const float inv = 1.0f / fmaxf((float)(e - b), 1.0f);
    float val = acc * inv;
    if (FINAL) val += radd[(size_t)v * D + lane];
    outbuf[(size_t)v * D + lane] = val;
  }
}

// ---------------------------------------------------------------------------
// Register-tiled fp32 GEMM: C[50000 x 128] = A[50000 x 128] @ W[128 x 128].
// MODE 0 (layer 1): A = [mean1 | x] (two 64-wide buffers),
//                   W = [Wl1 ; Wr1] (two 64x128), out = relu(C + bias) -> O0[N,128]
// MODE 1 (layer 2): A = h [N,128],
//                   W = [Wl2 | Wr2] (two 128x64),
//                   O0[N,64] = C[:,0:64] (p, no bias); O1[N,64] = C[:,64:128] + bias (r)
// Block: 256 threads, BM=64 rows, BN=128 (all), BK=32 (4 chunks).
// Thread tile: 4 rows x 8 cols (cols j0..j0+3 and 64+j0..64+j0+3).
//
// ROUND-4 LESSON: do NOT unroll the outer ck loop. Unrolling it replicated
// the stage+compute body 4x, the scheduler pipelined 24 in-flight float4
// staging loads, VGPR hit the 256 ceiling and spilled to scratch (2.2 GB/
// dispatch of scratch traffic, 15x slowdown). `#pragma unroll 1` + a
// 3-blocks/CU launch bound keeps the live set ~110 regs.
template <int MODE>
__global__ __launch_bounds__(256, 3) void gemm128(const float* __restrict__ A0,
                                                  const float* __restrict__ A1,
                                                  const float* __restrict__ W0,
                                                  const float* __restrict__ W1,
                                                  const float* __restrict__ bias,
                                                  float* __restrict__ O0,
                                                  float* __restrict__ O1) {
  constexpr int SAS = 36;  // sA row stride (pad 32->36: rows land on distinct banks)
  __shared__ float sA[64][SAS];
  __shared__ float sW[32][128];
  const int row0 = blockIdx.x * 64;
  const int tid = threadIdx.x;
  const int rowgrp = tid >> 4;   // 0..15
  const int colgrp = tid & 15;   // 0..15
  const int r0 = rowgrp * 4;
  const int j0 = colgrp * 4;

  float accA[4][4];  // cols j0..j0+3
  float accB[4][4];  // cols 64+j0..64+j0+3
#pragma unroll
  for (int r = 0; r < 4; ++r)
#pragma unroll
    for (int c = 0; c < 4; ++c) { accA[r][c] = 0.0f; accB[r][c] = 0.0f; }

#pragma unroll 1   // keep ONE copy of the body (see round-4 lesson above)
  for (int ck = 0; ck < 4; ++ck) {
    // --- stage sA: 64 rows x 32 k ---
#pragma unroll
    for (int v = 0; v < 2; ++v) {
      const int vid = v * 256 + tid;       // 0..511
      const int rr = vid >> 3;             // 0..63
      const int kq = (vid & 7) * 4;        // 0,4,...,28
      const int grow = row0 + rr;
      float4 val = make_float4(0.f, 0.f, 0.f, 0.f);
      if (grow < NNODES) {
        if (MODE == 0) {
          const float* src = (ck < 2) ? A0 : A1;
          const int kk = (ck & 1) * 32 + kq;
          val = *(const float4*)&src[(size_t)grow * 64 + kk];
        } else {
          val = *(const float4*)&A0[(size_t)grow * 128 + ck * 32 + kq];
        }
      }
      *(float4*)&sA[rr][kq] = val;
    }
    // --- stage sW: 32 k x 128 j ---
#pragma unroll
    for (int v = 0; v < 4; ++v) {
      const int vid = v * 256 + tid;       // 0..1023
      const int kk = vid >> 5;             // 0..31
      const int jq = (vid & 31) * 4;       // 0,4,...,124
      float4 w;
      if (MODE == 0) {
        const float* src = (ck < 2) ? W0 : W1;
        const int krel = (ck & 1) * 32 + kk;
        w = *(const float4*)&src[(size_t)krel * 128 + jq];
      } else {
        const int kg = ck * 32 + kk;
        const float* src = (jq < 64) ? W0 : W1;
        const int jrel = (jq < 64) ? jq : jq - 64;
        w = *(const float4*)&src[(size_t)kg * 64 + jrel];
      }
      *(float4*)&sW[kk][jq] = w;
    }
    __syncthreads();
    // --- compute: 32 k's, 128 FMA per 4-k group per thread ---
#pragma unroll
    for (int k4 = 0; k4 < 8; ++k4) {
      float4 a[4];
#pragma unroll
      for (int r = 0; r < 4; ++r) a[r] = *(const float4*)&sA[r0 + r][k4 * 4];
#pragma unroll
      for (int ki = 0; ki < 4; ++ki) {
        const float4 wlo = *(const float4*)&sW[k4 * 4 + ki][j0];
        const float4 whi = *(const float4*)&sW[k4 * 4 + ki][64 + j0];
#pragma unroll
        for (int r = 0; r < 4; ++r) {
          const float av = (ki == 0) ? a[r].x : (ki == 1) ? a[r].y
                         : (ki == 2) ? a[r].z : a[r].w;
          accA[r][0] = fmaf(av, wlo.x, accA[r][0]);
          accA[r][1] = fmaf(av, wlo.y, accA[r][1]);
          accA[r][2] = fmaf(av, wlo.z, accA[r][2]);
          accA[r][3] = fmaf(av, wlo.w, accA[r][3]);
          accB[r][0] = fmaf(av, whi.x, accB[r][0]);
          accB[r][1] = fmaf(av, whi.y, accB[r][1]);
          accB[r][2] = fmaf(av, whi.z, accB[r][2]);
          accB[r][3] = fmaf(av, whi.w, accB[r][3]);
        }
      }
    }
    __syncthreads();
  }

  // --- epilogue ---
  float4 blo = make_float4(0.f, 0.f, 0.f, 0.f);
  float4 bhi;
  if (MODE == 0) {
    blo = *(const float4*)&bias[j0];
    bhi = *(const float4*)&bias[64 + j0];
  } else {
    bhi = *(const float4*)&bias[j0];  // bias applies to r (upper half)
  }
#pragma unroll
  for (int r = 0; r < 4; ++r) {
    const int grow = row0 + r0 + r;
    if (grow >= NNODES) continue;
    float4 lo = make_float4(accA[r][0] + blo.x, accA[r][1] + blo.y,
                            accA[r][2] + blo.z, accA[r][3] + blo.w);
    float4 hi = make_float4(accB[r][0] + bhi.x, accB[r][1] + bhi.y,
                            accB[r][2] + bhi.z, accB[r][3] + bhi.w);
    if (MODE == 0) {
      lo.x = fmaxf(lo.x, 0.f); lo.y = fmaxf(lo.y, 0.f);
      lo.z = fmaxf(lo.z, 0.f); lo.w = fmaxf(lo.w, 0.f);
      hi.x = fmaxf(hi.x, 0.f); hi.y = fmaxf(hi.y, 0.f);
      hi.z = fmaxf(hi.z, 0.f); hi.w = fmaxf(hi.w, 0.f);
      *(float4*)&O0[(size_t)grow * 128 + j0] = lo;
      *(float4*)&O0[(size_t)grow * 128 + 64 + j0] = hi;
    } else {
      *(float4*)&O0[(size_t)grow * 64 + j0] = lo;   // p (no bias; blo==0)
      *(float4*)&O1[(size_t)grow * 64 + j0] = hi;   // r (+bl2)
    }
  }
}

}  // namespace

extern "C" void kernel_launch(void* const* d_in, const int* in_sizes, int n_in,
                              void* d_out, int out_size, void* d_ws, size_t ws_size,
                              hipStream_t stream) {
  const float* x   = (const float*)d_in[0];
  const void*  ei  = d_in[1];  // edge_index, int32 or int64 (detected at runtime)
  const float* Wl1 = (const float*)d_in[2];
  const float* bl1 = (const float*)d_in[3];
  const float* Wr1 = (const float*)d_in[4];
  const float* Wl2 = (const float*)d_in[5];
  const float* bl2 = (const float*)d_in[6];
  const float* Wr2 = (const float*)d_in[7];
  float* out = (float*)d_out;

  // Workspace layout (bytes):
  //   col     [E]    int32 @ 0          (3,200,000)
  //   flag    [1]    int32 @ 3,200,000  (256)
  //   deg     [N]    int32 @ 3,200,256  (200,000)   <- only memset target
  //   row_ptr [N+1]  int32 @ 3,400,256  (200,064)
  //   cursor  [N]    int32 @ 3,600,320  (200,000)
  //   bsum    [NBLK] int32 @ 3,800,320  (1,024 padded)
  //   mean1   [N,64] f32   @ 3,801,344  (12,800,000)  -- reused as r
  //   h       [N,128]f32   @ 16,601,344 (25,600,000)
  //   p       [N,64] f32   @ 42,201,344 (12,800,000)
  // total: 55,001,344 bytes
  char* ws = (char*)d_ws;
  int*   col     = (int*)(ws + 0);
  int*   flag    = (int*)(ws + 3200000);
  int*   deg     = (int*)(ws + 3200256);
  int*   row_ptr = (int*)(ws + 3400256);
  int*   cursor  = (int*)(ws + 3600320);
  int*   bsum    = (int*)(ws + 3800320);
  float* mean1   = (float*)(ws + 3801344);
  float* h       = (float*)(ws + 16601344);
  float* p       = (float*)(ws + 42201344);
  float* r       = mean1;  // safe: mean1's last read (gemm128<0>) precedes gemm128<1>'s write

  hipMemsetAsync(deg, 0, 200000, stream);

  // CSR build
  detect_idx64<<<1, 256, 0, stream>>>((const unsigned int*)ei, flag);
  deg_hist<<<1024, 256, 0, stream>>>(ei, flag, deg);
  scan_phase1<<<NBLK, 256, 0, stream>>>(deg, bsum);
  scan_phase2<<<1, 256, 0, stream>>>(bsum, row_ptr);
  scan_phase3<<<NBLK, 256, 0, stream>>>(deg, bsum, row_ptr, cursor);
  fill_csr<<<1024, 256, 0, stream>>>(ei, flag, cursor, col);

  constexpr int GEMM_BLOCKS = (NNODES + 63) / 64;  // 782

  // Layer 1: mean-aggregate x (gather, no atomics), then fused linear+relu
  seg_mean<DIN, false><<<12500, 256, 0, stream>>>(x, row_ptr, col, nullptr, mean1);
  gemm128<0><<<GEMM_BLOCKS, 256, 0, stream>>>(mean1, x, Wl1, Wr1, bl1, h, nullptr);

  // Layer 2: project first (mean commutes with linear), then gather + fused add
  gemm128<1><<<GEMM_BLOCKS, 256, 0, stream>>>(h, nullptr, Wl2, Wr2, bl2, p, r);
  seg_mean<DOUT, true><<<12500, 256, 0, stream>>>(p, row_ptr, col, r, out);
}